// Round 6
// baseline (3129.592 us; speedup 1.0000x reference)
//
#include <hip/hip_runtime.h>
#include <hip/hip_bf16.h>

// Problem dims (fixed)
#define NB 1024   // batch
#define NI 256    // input size
#define NH 256    // hidden
#define NT 64     // window T
#define TM1 63    // T-1 steps

typedef short bf16x8 __attribute__((ext_vector_type(8)));
typedef float f32x4 __attribute__((ext_vector_type(4)));

__device__ __forceinline__ float bf16s_to_f(short s){
    unsigned u = ((unsigned)(unsigned short)s) << 16;
    return __builtin_bit_cast(float, u);
}
__device__ __forceinline__ unsigned short f_to_bf16s(float f){
    __hip_bfloat16 h = __float2bfloat16(f);
    return *(unsigned short*)&h;
}
__device__ __forceinline__ unsigned pack_bf16(float lo, float hi){
    return (unsigned)f_to_bf16s(lo) | ((unsigned)f_to_bf16s(hi) << 16);
}

__device__ __forceinline__ float fast_exp2(float x){ return __builtin_amdgcn_exp2f(x); }
__device__ __forceinline__ float fast_rcp(float x){ return __builtin_amdgcn_rcpf(x); }
__device__ __forceinline__ float fast_tanh(float x){
    float e = fast_exp2(x * 2.8853900817779268f);   // 2*log2(e)
    return 1.f - 2.f * fast_rcp(e + 1.f);
}
__device__ __forceinline__ float fast_sigmoid(float x){
    return fast_rcp(1.f + fast_exp2(-1.4426950408889634f * x));
}

// ---------------------------------------------------------------------------
// One-time prep.
// blocks 0..1023:  W2[n][k] = bf16(k<256 ? Wih[n][k] : Whh[n][k-256]); bias=bih+bhh
// blocks 1024..1151: WhT[u][k] = bf16(Wh[k][u])  (bf16 transpose, k=0..511 = [h|c])
// ---------------------------------------------------------------------------
__global__ __launch_bounds__(256) void prep_w2(
    const float* __restrict__ Wih, const float* __restrict__ Whh,
    const float* __restrict__ bih, const float* __restrict__ bhh,
    const float* __restrict__ Wh,
    __hip_bfloat16* __restrict__ W2, float* __restrict__ bias,
    __hip_bfloat16* __restrict__ WhT)
{
    int tid = threadIdx.x;
    if (blockIdx.x < 1024){
        int n = blockIdx.x;
        W2[(long)n*512 + tid]       = __float2bfloat16(Wih[(long)n*256 + tid]);
        W2[(long)n*512 + 256 + tid] = __float2bfloat16(Whh[(long)n*256 + tid]);
        if (tid == 0) bias[n] = bih[n] + bhh[n];
    } else {
        int idx = (blockIdx.x - 1024) * 256 + tid;   // 0..32767
        int u = idx >> 9;          // 0..63
        int k = idx & 511;         // 0..511
        WhT[idx] = __float2bfloat16(Wh[k*NT + u]);   // WhT[u][k] = Wh[k][u]
    }
}

// ---------------------------------------------------------------------------
// prefsT[b][i][u] = b_fs[u] + sum_t FS[b][t][i]*W_fs[t][u]   (bf16, u-contig)
// ---------------------------------------------------------------------------
__global__ __launch_bounds__(256) void prefs_kernel(
    const float* __restrict__ FS,    // [B][63][I] f32
    const float* __restrict__ Wfs,   // [64][64]   f32
    const float* __restrict__ bfs,   // [64]       f32
    __hip_bfloat16* __restrict__ prefsT)  // [B][I][64] bf16
{
    __shared__ float wfs_s[TM1][NT];
    int b = blockIdx.x, tid = threadIdx.x;
    for (int idx = tid; idx < TM1*NT; idx += 256)
        wfs_s[idx >> 6][idx & 63] = Wfs[idx];
    __syncthreads();

    const float* fsp = FS + (long)b*TM1*NI + tid;

    f32x4 acc[16];
    #pragma unroll
    for (int g = 0; g < 16; ++g) acc[g] = *(const f32x4*)(bfs + g*4);

    #pragma unroll 4
    for (int t = 0; t < TM1; ++t){
        float fs = fsp[(long)t*NI];
        #pragma unroll
        for (int g = 0; g < 16; ++g){
            f32x4 w4 = *(const f32x4*)&wfs_s[t][g*4];
            acc[g] += fs * w4;
        }
    }

    uint4* dst = (uint4*)(prefsT + ((long)b*NI + tid)*NT);
    #pragma unroll
    for (int g = 0; g < 16; g += 2){
        uint4 v;
        v.x = pack_bf16(acc[g][0],   acc[g][1]);
        v.y = pack_bf16(acc[g][2],   acc[g][3]);
        v.z = pack_bf16(acc[g+1][0], acc[g+1][1]);
        v.w = pack_bf16(acc[g+1][2], acc[g+1][3]);
        dst[g >> 1] = v;
    }
}

// ---------------------------------------------------------------------------
// Batch-local recurrent kernel: 256 blocks x 1024 threads (16 waves = 4/SIMD),
// 4 batches/block. prefsT (t-invariant, 128 KB) staged in LDS once.
// Per step:
//   S: s2 = [h|c] @ WhT  split-K over 16 waves (4 kq x 4 u-tiles, 4-MFMA chain),
//      partials via gates_s scratch, reduced in finalize.
//   A: tanh/softmax attention; thread -> 1 batch (bb=tid>>8), 64 tanh.
//   B: gates = [w_in|h] @ W2^T; wave owns 64 rows; kc-outer / d-inner loop ->
//      4 independent MFMA chains/wave; Af re-read per kc from LDS (VGPR<=128).
//   pointwise: single pass, 1024 threads cover 4x256.
// MFMA 16x16x32 bf16; A: m=lane&15,k=(lane>>4)*8+j ; B: n=lane&15, same k ;
// C/D: col=lane&15, row=(lane>>4)*4+reg   [learn_hip m89-verified]
// ---------------------------------------------------------------------------
__global__ __launch_bounds__(1024) void recurrent_kernel(
    const float* __restrict__ FS,       // [B][63][I]
    const float* __restrict__ yhist,    // [B][63]
    const float* __restrict__ bh,       // [64]
    const float* __restrict__ Wfs,      // [64][64] (last row used)
    const float* __restrict__ Wattn,    // [64]
    const float* __restrict__ battn,    // [1]
    const __hip_bfloat16* __restrict__ prefsT,  // [B][I][64]
    const __hip_bfloat16* __restrict__ W2,      // [1024][512]
    const float* __restrict__ bias,             // [1024]
    const __hip_bfloat16* __restrict__ WhT,     // [64][512]
    float* __restrict__ out_iw,         // [B][63][I] f32
    float* __restrict__ out_ie)         // [B][63][H] f32
{
    __shared__ __align__(16) __hip_bfloat16 pf_lds[8][4][256][8];  // 128 KB, t-invariant
    __shared__ __align__(16) __hip_bfloat16 hcq[4][776];  // [w_in(256)|h(256)|c(256)]+pad
    __shared__ __align__(16) float c_s[4][260];
    __shared__ __align__(16) float gates_s[4][1028];      // B-results; S-partial scratch
    __shared__ __align__(16) float s2_s[4][68];
    __shared__ __align__(16) float bh_s[NT], wfsl_s[NT], wattn_s[NT];
    __shared__ float yh_s[4][NT];
    __shared__ float redm[4][4], reds[4][4];
    __shared__ float battn_s;

    int tid  = threadIdx.x;
    int b0   = blockIdx.x * 4;
    int wave = tid >> 6, lane = tid & 63;
    int lm   = lane & 15, lk = (lane >> 4) * 8;
    int brow = lm & 3;                      // batch row for MFMA A (rows 4-15 dup)

    // phase A ids: thread -> (batch ab, input ai); 4 waves per batch group
    int ab = tid >> 8, ai = tid & 255, agw = (tid >> 6) & 3;
    // phase S ids: wave -> (k-quarter kq, u-tile u0)
    int kq = wave >> 2, u0 = (wave & 3) * 16;
    // phase B id: wave -> 64 output rows starting at n0
    int n0 = wave * 64;
    // pointwise ids
    int pb = tid >> 8, pj = tid & 255;

    // ---- one-time staging ----
    // prefsT -> LDS (t-invariant): [o][bb][i][8], lane-contiguous reads
    {
        const bf16x8* src = (const bf16x8*)(prefsT + ((long)(b0+ab)*NI + ai)*NT);
        #pragma unroll
        for (int o = 0; o < 8; ++o)
            *(bf16x8*)&pf_lds[o][ab][ai][0] = src[o];
    }
    if (tid < 256){   // yhist row per batch, once
        int bb = tid >> 6, tt = tid & 63;
        if (tt < TM1) yh_s[bb][tt] = yhist[(b0 + bb)*TM1 + tt];
    }
    if (tid < NT){
        bh_s[tid]    = bh[tid];
        wfsl_s[tid]  = Wfs[TM1*NT + tid];
        wattn_s[tid] = Wattn[tid];
    }
    if (tid == 64) battn_s = battn[0];
    // bias in per-thread regs for pointwise: br[q] = bias[q*256 + pj]
    float br[4];
    #pragma unroll
    for (int q = 0; q < 4; ++q) br[q] = bias[q*256 + pj];
    {   // zero state: h, c halves of hcq + f32 c
        hcq[pb][256 + pj] = __float2bfloat16(0.f);
        hcq[pb][512 + pj] = __float2bfloat16(0.f);
        c_s[pb][pj]       = 0.f;
    }
    __syncthreads();

    for (int t = 0; t < TM1; ++t){
        // FS prefetch (used at end of phase A; latency hidden under S)
        float fsv = __builtin_nontemporal_load(
            FS + ((long)(b0+ab)*TM1 + t)*NI + ai);

        // ---------------- Phase S: s2 = [h|c] @ WhT, split-K x16 waves ------
        {
            const __hip_bfloat16* wrow = WhT + (long)(u0 + lm)*512 + lk;
            f32x4 sacc = {};
            #pragma unroll
            for (int kk = 0; kk < 4; ++kk){
                int kc = kq*4 + kk;
                bf16x8 af = *(const bf16x8*)&hcq[brow][256 + kc*32 + lk];
                bf16x8 bf = *(const bf16x8*)(wrow + kc*32);
                sacc = __builtin_amdgcn_mfma_f32_16x16x32_bf16(af, bf, sacc, 0, 0, 0);
            }
            if (lane < 16){
                #pragma unroll
                for (int r = 0; r < 4; ++r)
                    gates_s[r][kq*256 + u0 + lane] = sacc[r];
            }
        }
        __syncthreads();
        if (tid < 256){   // finalize: reduce 4 k-quarters + bh + y*wfs_last
            int bb = tid >> 6, u = tid & 63;
            s2_s[bb][u] = gates_s[bb][u] + gates_s[bb][256 + u]
                        + gates_s[bb][512 + u] + gates_s[bb][768 + u]
                        + bh_s[u] + yh_s[bb][t] * wfsl_s[u];
        }
        __syncthreads();

        // ---------------- Phase A: attention (thread -> 1 batch) ------------
        float attn;
        {
            float acc0 = 0.f, acc1 = 0.f;
            #pragma unroll
            for (int o = 0; o < 8; ++o){
                bf16x8 pf = *(const bf16x8*)&pf_lds[o][ab][ai][0];
                f32x4 sa = *(const f32x4*)&s2_s[ab][o*8];
                f32x4 sb = *(const f32x4*)&s2_s[ab][o*8 + 4];
                f32x4 wa = *(const f32x4*)&wattn_s[o*8];
                f32x4 wb = *(const f32x4*)&wattn_s[o*8 + 4];
                #pragma unroll
                for (int j = 0; j < 4; ++j){
                    acc0 = fmaf(fast_tanh(sa[j] + bf16s_to_f(pf[j])),   wa[j], acc0);
                    acc1 = fmaf(fast_tanh(sb[j] + bf16s_to_f(pf[j+4])), wb[j], acc1);
                }
            }
            attn = acc0 + acc1 + battn_s;
        }

        // softmax over the batch group's 256 threads (4 waves)
        {
            float m = attn;
            #pragma unroll
            for (int o = 32; o > 0; o >>= 1) m = fmaxf(m, __shfl_xor(m, o, 64));
            if (lane == 0) redm[ab][agw] = m;
        }
        __syncthreads();
        float pexp;
        {
            float m = fmaxf(fmaxf(redm[ab][0], redm[ab][1]),
                            fmaxf(redm[ab][2], redm[ab][3]));
            pexp = fast_exp2((attn - m) * 1.4426950408889634f);
            float ss = pexp;
            #pragma unroll
            for (int o = 32; o > 0; o >>= 1) ss += __shfl_xor(ss, o, 64);
            if (lane == 0) reds[ab][agw] = ss;
        }
        __syncthreads();
        {
            float ss = reds[ab][0] + reds[ab][1] + reds[ab][2] + reds[ab][3];
            float w = pexp * fast_rcp(ss) * fsv;
            hcq[ab][ai] = __float2bfloat16(w);
            __builtin_nontemporal_store(w,
                out_iw + ((long)(b0+ab)*TM1 + t)*NI + ai);
        }
        __syncthreads();

        // ---------------- Phase B: gates GEMM (wave -> 64 rows) -------------
        {
            const __hip_bfloat16* wbase = W2 + (long)(n0 + lm)*512 + lk;
            f32x4 acc[4] = {};
            #pragma unroll
            for (int kc = 0; kc < 16; ++kc){
                bf16x8 af = *(const bf16x8*)&hcq[brow][kc*32 + lk];
                #pragma unroll
                for (int d = 0; d < 4; ++d){
                    bf16x8 bfrag = *(const bf16x8*)(wbase + (long)d*16*512 + kc*32);
                    acc[d] = __builtin_amdgcn_mfma_f32_16x16x32_bf16(af, bfrag, acc[d], 0, 0, 0);
                }
            }
            if (lane < 16){
                #pragma unroll
                for (int d = 0; d < 4; ++d)
                    #pragma unroll
                    for (int r = 0; r < 4; ++r)
                        gates_s[r][n0 + d*16 + lane] = acc[d][r];
            }
        }
        __syncthreads();
        {   // pointwise: single pass, 1024 threads cover 4 batches x 256 j
            float ig = gates_s[pb][pj]       + br[0];
            float fg = gates_s[pb][256 + pj] + br[1];
            float gg = gates_s[pb][512 + pj] + br[2];
            float og = gates_s[pb][768 + pj] + br[3];
            float cold = c_s[pb][pj];
            float cn = fast_sigmoid(fg)*cold + fast_sigmoid(ig)*fast_tanh(gg);
            float hn = fast_sigmoid(og)*fast_tanh(cn);
            c_s[pb][pj]       = cn;
            hcq[pb][256 + pj] = __float2bfloat16(hn);
            hcq[pb][512 + pj] = __float2bfloat16(cn);
            __builtin_nontemporal_store(hn,
                out_ie + ((long)(b0+pb)*TM1 + t)*NH + pj);
        }
        __syncthreads();
    }
}

// ---------------------------------------------------------------------------
extern "C" void kernel_launch(void* const* d_in, const int* in_sizes, int n_in,
                              void* d_out, int out_size, void* d_ws, size_t ws_size,
                              hipStream_t stream)
{
    const float* FS    = (const float*)d_in[0];
    const float* yh    = (const float*)d_in[1];
    const float* Wh    = (const float*)d_in[2];
    const float* bh    = (const float*)d_in[3];
    const float* Wfs   = (const float*)d_in[4];
    const float* bfs   = (const float*)d_in[5];
    const float* Wattn = (const float*)d_in[6];
    const float* battn = (const float*)d_in[7];
    const float* Wih   = (const float*)d_in[8];
    const float* Whh   = (const float*)d_in[9];
    const float* bih   = (const float*)d_in[10];
    const float* bhh   = (const float*)d_in[11];

    char* ws = (char*)d_ws;
    const size_t MB = 1048576;
    // layout: prefsT 32MB | W2 1MB | bias 4KB | WhT 64KB
    __hip_bfloat16* prefsT = (__hip_bfloat16*)ws;
    size_t off = (size_t)NB * NI * NT * sizeof(__hip_bfloat16);   // 32 MB
    __hip_bfloat16* W2  = (__hip_bfloat16*)(ws + off);
    float* bias         = (float*)(ws + off + 1*MB);
    __hip_bfloat16* WhT = (__hip_bfloat16*)(ws + off + 1*MB + 4096);

    float* out_iw = (float*)d_out;                     // [B][63][I] f32
    float* out_ie = out_iw + (size_t)NB * TM1 * NI;    // [B][63][H] f32

    prep_w2<<<1152, 256, 0, stream>>>(Wih, Whh, bih, bhh, Wh, W2, bias, WhT);
    prefs_kernel<<<NB, 256, 0, stream>>>(FS, Wfs, bfs, prefsT);
    recurrent_kernel<<<256, 1024, 0, stream>>>(FS, yh, bh, Wfs, Wattn, battn,
                                               prefsT, W2, bias, WhT,
                                               out_iw, out_ie);
}

// Round 7
// 2604.907 us; speedup vs baseline: 1.2014x; 1.2014x over previous
//
#include <hip/hip_runtime.h>
#include <hip/hip_bf16.h>

// Problem dims (fixed)
#define NB 1024   // batch
#define NI 256    // input size
#define NH 256    // hidden
#define NT 64     // window T
#define TM1 63    // T-1 steps

typedef short bf16x8 __attribute__((ext_vector_type(8)));
typedef float f32x4 __attribute__((ext_vector_type(4)));

__device__ __forceinline__ float bf16s_to_f(short s){
    unsigned u = ((unsigned)(unsigned short)s) << 16;
    return __builtin_bit_cast(float, u);
}
__device__ __forceinline__ unsigned short f_to_bf16s(float f){
    __hip_bfloat16 h = __float2bfloat16(f);
    return *(unsigned short*)&h;
}
__device__ __forceinline__ unsigned pack_bf16(float lo, float hi){
    return (unsigned)f_to_bf16s(lo) | ((unsigned)f_to_bf16s(hi) << 16);
}

__device__ __forceinline__ float fast_exp2(float x){ return __builtin_amdgcn_exp2f(x); }
__device__ __forceinline__ float fast_rcp(float x){ return __builtin_amdgcn_rcpf(x); }
__device__ __forceinline__ float fast_tanh(float x){
    float e = fast_exp2(x * 2.8853900817779268f);   // 2*log2(e)
    return 1.f - 2.f * fast_rcp(e + 1.f);
}
__device__ __forceinline__ float fast_sigmoid(float x){
    return fast_rcp(1.f + fast_exp2(-1.4426950408889634f * x));
}

// ---------------------------------------------------------------------------
// One-time prep.
// blocks 0..1023:  W2[n][k] = bf16(k<256 ? Wih[n][k] : Whh[n][k-256]); bias=bih+bhh
// blocks 1024..1151: WhT[u][k] = bf16(Wh[k][u])  (bf16 transpose, k=0..511 = [h|c])
// ---------------------------------------------------------------------------
__global__ __launch_bounds__(256) void prep_w2(
    const float* __restrict__ Wih, const float* __restrict__ Whh,
    const float* __restrict__ bih, const float* __restrict__ bhh,
    const float* __restrict__ Wh,
    __hip_bfloat16* __restrict__ W2, float* __restrict__ bias,
    __hip_bfloat16* __restrict__ WhT)
{
    int tid = threadIdx.x;
    if (blockIdx.x < 1024){
        int n = blockIdx.x;
        W2[(long)n*512 + tid]       = __float2bfloat16(Wih[(long)n*256 + tid]);
        W2[(long)n*512 + 256 + tid] = __float2bfloat16(Whh[(long)n*256 + tid]);
        if (tid == 0) bias[n] = bih[n] + bhh[n];
    } else {
        int idx = (blockIdx.x - 1024) * 256 + tid;   // 0..32767
        int u = idx >> 9;          // 0..63
        int k = idx & 511;         // 0..511
        WhT[idx] = __float2bfloat16(Wh[k*NT + u]);   // WhT[u][k] = Wh[k][u]
    }
}

// ---------------------------------------------------------------------------
// prefsT[b][i][u] = b_fs[u] + sum_t FS[b][t][i]*W_fs[t][u]   (bf16, u-contig)
// ---------------------------------------------------------------------------
__global__ __launch_bounds__(256) void prefs_kernel(
    const float* __restrict__ FS,    // [B][63][I] f32
    const float* __restrict__ Wfs,   // [64][64]   f32
    const float* __restrict__ bfs,   // [64]       f32
    __hip_bfloat16* __restrict__ prefsT)  // [B][I][64] bf16
{
    __shared__ float wfs_s[TM1][NT];
    int b = blockIdx.x, tid = threadIdx.x;
    for (int idx = tid; idx < TM1*NT; idx += 256)
        wfs_s[idx >> 6][idx & 63] = Wfs[idx];
    __syncthreads();

    const float* fsp = FS + (long)b*TM1*NI + tid;

    f32x4 acc[16];
    #pragma unroll
    for (int g = 0; g < 16; ++g) acc[g] = *(const f32x4*)(bfs + g*4);

    #pragma unroll 4
    for (int t = 0; t < TM1; ++t){
        float fs = fsp[(long)t*NI];
        #pragma unroll
        for (int g = 0; g < 16; ++g){
            f32x4 w4 = *(const f32x4*)&wfs_s[t][g*4];
            acc[g] += fs * w4;
        }
    }

    uint4* dst = (uint4*)(prefsT + ((long)b*NI + tid)*NT);
    #pragma unroll
    for (int g = 0; g < 16; g += 2){
        uint4 v;
        v.x = pack_bf16(acc[g][0],   acc[g][1]);
        v.y = pack_bf16(acc[g][2],   acc[g][3]);
        v.z = pack_bf16(acc[g+1][0], acc[g+1][1]);
        v.w = pack_bf16(acc[g+1][2], acc[g+1][3]);
        dst[g >> 1] = v;
    }
}

// ---------------------------------------------------------------------------
// Batch-local recurrent kernel: 256 blocks x 1024 threads (16 waves = 4/SIMD),
// 4 batches/block, 1 block/CU. prefs slice held in REGISTERS (32 VGPR/thread,
// thread -> one (batch, i) pair) -> LDS ~79 KB, no pf staging traffic.
// Per step:
//   S: s2 = [h|c] @ WhT, split-K over 16 waves (4 kq x 4 u-tiles), partials
//      through gpart[0] scratch, reduced in finalize.       [r6-verified]
//   A: tanh/softmax attention, thread -> 1 batch, pf from regs. [r6-verified]
//   B: gates = [w_in|h] @ W2^T; 16 waves = 4 n-quarters x 4 k-segments.
//      Each quarter's 4 waves sweep the SAME contiguous 256-row region
//      (round-5's L2-friendly macro pattern), d-outer/kc-inner, unroll 2.
//      Split-K partials in gpart[ks], reduced in the pointwise pass.
// MFMA 16x16x32 bf16; A: m=lane&15,k=(lane>>4)*8+j ; B: n=lane&15, same k ;
// C/D: col=lane&15, row=(lane>>4)*4+reg   [learn_hip m89-verified]
// ---------------------------------------------------------------------------
__global__ __launch_bounds__(1024, 4) void recurrent_kernel(
    const float* __restrict__ FS,       // [B][63][I]
    const float* __restrict__ yhist,    // [B][63]
    const float* __restrict__ bh,       // [64]
    const float* __restrict__ Wfs,      // [64][64] (last row used)
    const float* __restrict__ Wattn,    // [64]
    const float* __restrict__ battn,    // [1]
    const __hip_bfloat16* __restrict__ prefsT,  // [B][I][64]
    const __hip_bfloat16* __restrict__ W2,      // [1024][512]
    const float* __restrict__ bias,             // [1024]
    const __hip_bfloat16* __restrict__ WhT,     // [64][512]
    float* __restrict__ out_iw,         // [B][63][I] f32
    float* __restrict__ out_ie)         // [B][63][H] f32
{
    __shared__ __align__(16) float gpart[4][4][1032];     // [kseg][batch][n] 66 KB
    __shared__ __align__(16) __hip_bfloat16 hcq[4][776];  // [w_in(256)|h(256)|c(256)]
    __shared__ __align__(16) float c_s[4][260];
    __shared__ __align__(16) float s2_s[4][68];
    __shared__ __align__(16) float bh_s[NT], wfsl_s[NT], wattn_s[NT];
    __shared__ float yh_s[4][NT];
    __shared__ float redm[4][4], reds[4][4];
    __shared__ float battn_s;

    int tid  = threadIdx.x;
    int b0   = blockIdx.x * 4;
    int wave = tid >> 6, lane = tid & 63;
    int lm   = lane & 15, lk = (lane >> 4) * 8;
    int brow = lm & 3;                      // batch row for MFMA A (rows 4-15 dup)

    // phase A ids: thread -> (batch ab, input ai)
    int ab = tid >> 8, ai = tid & 255, agw = (tid >> 6) & 3;
    // phase S ids: wave -> (k-quarter kq, u-tile u0s)
    int kq = wave >> 2, u0s = (wave & 3) * 16;
    // phase B ids: wave -> (n-quarter q, k-segment ks)
    int q = wave & 3, ks = wave >> 2;
    // pointwise ids
    int pb = tid >> 8, pj = tid & 255;

    // ---- one-time staging ----
    // prefs slice -> REGISTERS (t-invariant, 32 VGPR)
    bf16x8 pf[8];
    {
        const bf16x8* src = (const bf16x8*)(prefsT + ((long)(b0+ab)*NI + ai)*NT);
        #pragma unroll
        for (int o = 0; o < 8; ++o) pf[o] = src[o];
    }
    if (tid < 256){   // yhist row per batch, once
        int bb = tid >> 6, tt = tid & 63;
        if (tt < TM1) yh_s[bb][tt] = yhist[(b0 + bb)*TM1 + tt];
    }
    if (tid < NT){
        bh_s[tid]    = bh[tid];
        wfsl_s[tid]  = Wfs[TM1*NT + tid];
        wattn_s[tid] = Wattn[tid];
    }
    if (tid == 64) battn_s = battn[0];
    // bias in per-thread regs for pointwise
    float br[4];
    #pragma unroll
    for (int g = 0; g < 4; ++g) br[g] = bias[g*256 + pj];
    {   // zero state: h, c halves of hcq + f32 c
        hcq[pb][256 + pj] = __float2bfloat16(0.f);
        hcq[pb][512 + pj] = __float2bfloat16(0.f);
        c_s[pb][pj]       = 0.f;
    }
    __syncthreads();

    for (int t = 0; t < TM1; ++t){
        // FS prefetch (used after softmax; latency hidden under S+A)
        float fsv = __builtin_nontemporal_load(
            FS + ((long)(b0+ab)*TM1 + t)*NI + ai);

        // ---------------- Phase S: s2 = [h|c] @ WhT, split-K x16 waves ------
        {
            const __hip_bfloat16* wrow = WhT + (long)(u0s + lm)*512 + lk;
            f32x4 sacc = {};
            #pragma unroll
            for (int kk = 0; kk < 4; ++kk){
                int kc = kq*4 + kk;
                bf16x8 af = *(const bf16x8*)&hcq[brow][256 + kc*32 + lk];
                bf16x8 bf = *(const bf16x8*)(wrow + kc*32);
                sacc = __builtin_amdgcn_mfma_f32_16x16x32_bf16(af, bf, sacc, 0, 0, 0);
            }
            if (lane < 16){
                #pragma unroll
                for (int r = 0; r < 4; ++r)
                    gpart[0][r][kq*256 + u0s + lane] = sacc[r];
            }
        }
        __syncthreads();
        if (tid < 256){   // finalize: reduce 4 k-quarters + bh + y*wfs_last
            int bb = tid >> 6, u = tid & 63;
            s2_s[bb][u] = gpart[0][bb][u] + gpart[0][bb][256 + u]
                        + gpart[0][bb][512 + u] + gpart[0][bb][768 + u]
                        + bh_s[u] + yh_s[bb][t] * wfsl_s[u];
        }
        __syncthreads();

        // ---------------- Phase A: attention (thread -> 1 batch, pf regs) ---
        float attn;
        {
            float acc0 = 0.f, acc1 = 0.f;
            #pragma unroll
            for (int o = 0; o < 8; ++o){
                f32x4 sa = *(const f32x4*)&s2_s[ab][o*8];
                f32x4 sb = *(const f32x4*)&s2_s[ab][o*8 + 4];
                f32x4 wa = *(const f32x4*)&wattn_s[o*8];
                f32x4 wb = *(const f32x4*)&wattn_s[o*8 + 4];
                #pragma unroll
                for (int j = 0; j < 4; ++j){
                    acc0 = fmaf(fast_tanh(sa[j] + bf16s_to_f(pf[o][j])),   wa[j], acc0);
                    acc1 = fmaf(fast_tanh(sb[j] + bf16s_to_f(pf[o][j+4])), wb[j], acc1);
                }
            }
            attn = acc0 + acc1 + battn_s;
        }

        // softmax over the batch group's 256 threads (4 waves)
        {
            float m = attn;
            #pragma unroll
            for (int o = 32; o > 0; o >>= 1) m = fmaxf(m, __shfl_xor(m, o, 64));
            if (lane == 0) redm[ab][agw] = m;
        }
        __syncthreads();
        float pexp;
        {
            float m = fmaxf(fmaxf(redm[ab][0], redm[ab][1]),
                            fmaxf(redm[ab][2], redm[ab][3]));
            pexp = fast_exp2((attn - m) * 1.4426950408889634f);
            float ss = pexp;
            #pragma unroll
            for (int o = 32; o > 0; o >>= 1) ss += __shfl_xor(ss, o, 64);
            if (lane == 0) reds[ab][agw] = ss;
        }
        __syncthreads();
        {
            float ss = reds[ab][0] + reds[ab][1] + reds[ab][2] + reds[ab][3];
            float w = pexp * fast_rcp(ss) * fsv;
            hcq[ab][ai] = __float2bfloat16(w);
            __builtin_nontemporal_store(w,
                out_iw + ((long)(b0+ab)*TM1 + t)*NI + ai);
        }
        __syncthreads();

        // ---------------- Phase B: gates GEMM, 4 quarters x 4 ksegs ---------
        {
            // wave (q, ks): rows q*256 + d*16 + lm, cols (ks*4 + kk)*32 + lk
            const __hip_bfloat16* wq = W2 + (long)(q*256 + lm)*512 + ks*128 + lk;
            #pragma unroll 4
            for (int d = 0; d < 16; d += 2){
                const __hip_bfloat16* w0 = wq + (long)(d*16)*512;
                const __hip_bfloat16* w1 = w0 + (long)16*512;
                f32x4 a0 = {}, a1 = {};
                #pragma unroll
                for (int kk = 0; kk < 4; ++kk){
                    int kc = ks*4 + kk;
                    bf16x8 af = *(const bf16x8*)&hcq[brow][kc*32 + lk];
                    bf16x8 f0 = *(const bf16x8*)(w0 + kk*32);
                    bf16x8 f1 = *(const bf16x8*)(w1 + kk*32);
                    a0 = __builtin_amdgcn_mfma_f32_16x16x32_bf16(af, f0, a0, 0, 0, 0);
                    a1 = __builtin_amdgcn_mfma_f32_16x16x32_bf16(af, f1, a1, 0, 0, 0);
                }
                if (lane < 16){
                    #pragma unroll
                    for (int r = 0; r < 4; ++r){
                        gpart[ks][r][q*256 + d*16 + lane]     = a0[r];
                        gpart[ks][r][q*256 + d*16 + 16 + lane] = a1[r];
                    }
                }
            }
        }
        __syncthreads();
        {   // pointwise: reduce 4 ksegs + bias, LSTM update
            float g4[4];
            #pragma unroll
            for (int g = 0; g < 4; ++g){
                int n = g*256 + pj;
                g4[g] = gpart[0][pb][n] + gpart[1][pb][n]
                      + gpart[2][pb][n] + gpart[3][pb][n] + br[g];
            }
            float cold = c_s[pb][pj];
            float cn = fast_sigmoid(g4[1])*cold + fast_sigmoid(g4[0])*fast_tanh(g4[2]);
            float hn = fast_sigmoid(g4[3])*fast_tanh(cn);
            c_s[pb][pj]       = cn;
            hcq[pb][256 + pj] = __float2bfloat16(hn);
            hcq[pb][512 + pj] = __float2bfloat16(cn);
            __builtin_nontemporal_store(hn,
                out_ie + ((long)(b0+pb)*TM1 + t)*NH + pj);
        }
        __syncthreads();
    }
}

// ---------------------------------------------------------------------------
extern "C" void kernel_launch(void* const* d_in, const int* in_sizes, int n_in,
                              void* d_out, int out_size, void* d_ws, size_t ws_size,
                              hipStream_t stream)
{
    const float* FS    = (const float*)d_in[0];
    const float* yh    = (const float*)d_in[1];
    const float* Wh    = (const float*)d_in[2];
    const float* bh    = (const float*)d_in[3];
    const float* Wfs   = (const float*)d_in[4];
    const float* bfs   = (const float*)d_in[5];
    const float* Wattn = (const float*)d_in[6];
    const float* battn = (const float*)d_in[7];
    const float* Wih   = (const float*)d_in[8];
    const float* Whh   = (const float*)d_in[9];
    const float* bih   = (const float*)d_in[10];
    const float* bhh   = (const float*)d_in[11];

    char* ws = (char*)d_ws;
    const size_t MB = 1048576;
    // layout: prefsT 32MB | W2 1MB | bias 4KB | WhT 64KB
    __hip_bfloat16* prefsT = (__hip_bfloat16*)ws;
    size_t off = (size_t)NB * NI * NT * sizeof(__hip_bfloat16);   // 32 MB
    __hip_bfloat16* W2  = (__hip_bfloat16*)(ws + off);
    float* bias         = (float*)(ws + off + 1*MB);
    __hip_bfloat16* WhT = (__hip_bfloat16*)(ws + off + 1*MB + 4096);

    float* out_iw = (float*)d_out;                     // [B][63][I] f32
    float* out_ie = out_iw + (size_t)NB * TM1 * NI;    // [B][63][H] f32

    prep_w2<<<1152, 256, 0, stream>>>(Wih, Whh, bih, bhh, Wh, W2, bias, WhT);
    prefs_kernel<<<NB, 256, 0, stream>>>(FS, Wfs, bfs, prefsT);
    recurrent_kernel<<<256, 1024, 0, stream>>>(FS, yh, bh, Wfs, Wattn, battn,
                                               prefsT, W2, bias, WhT,
                                               out_iw, out_ie);
}